// Round 7
// baseline (419.003 us; speedup 1.0000x reference)
//
#include <hip/hip_runtime.h>
#include <stdint.h>

// ---------------------------------------------------------------------------
// DkNN round 11: fused convert+GEMM, B-resident-in-LDS (round-10 structure,
// FIXED: phase-1 conversion loop covered only half of each half-row —
// g2 < 4 -> g2 < 8; each thread's 128 floats = 16 chunks, 2 chunks/iter).
//  - prep_q: query side only (normalize, center, Ah bf16-hi, xqf, norms).
//  - fused_tile: each block owns one 128-row train n-tile x one 512-query
//    m-half. Phase 1: read X fp32, convert to bf16 RN directly into LDS
//    (full K=256 resident, swizzled), compute row norms (xn2 + global maxb).
//    Phase 2: 4 m-tiles x 4 K-steps; only A staged (16 KB/step, 2 bufs,
//    single-barrier pipeline). Epilogue per m-tile: per-(query, 64-col
//    group) min of xn2 - 2*dot -> gmin.  Bh never touches HBM.
//  - select_classify: unchanged (window from rigorous bound, exact fp32
//    rescore, fused conformal classification).
// ---------------------------------------------------------------------------

typedef __attribute__((ext_vector_type(8))) short short8;   // 8 bf16 = 4 VGPR
typedef __attribute__((ext_vector_type(4))) float float4v;  // MFMA C/D

static __device__ __forceinline__ unsigned short bf16_rn(float f) {
    unsigned int u = __float_as_uint(f);
    unsigned int r = (u + 0x7FFFu + ((u >> 16) & 1u)) >> 16;
    return (unsigned short)r;
}

static __device__ __forceinline__ void gload_lds16(const void* g, void* l) {
    __builtin_amdgcn_global_load_lds(
        (const __attribute__((address_space(1))) unsigned int*)g,
        (__attribute__((address_space(3))) unsigned int*)l, 16, 0, 0);
}

// One block per query row: normalize, center, bf16-hi split, norms.
__global__ __launch_bounds__(256) void prep_q(
    const float* __restrict__ x, const float* __restrict__ center,
    unsigned short* __restrict__ Ah, float* __restrict__ xqf,
    float* __restrict__ q2a, float* __restrict__ al2q, int B, int Mp)
{
    const int tid = threadIdx.x;
    const int row = blockIdx.x;
    __shared__ float p1[4], p2[4], p3[4];
    if (row >= Mp) return;
    if (row >= B) {
        Ah[(size_t)row * 256 + tid] = 0;
        xqf[(size_t)row * 256 + tid] = 0.f;
        if (tid == 0) { q2a[row] = 0.f; al2q[row] = 0.f; }
        return;
    }
    float v = x[(size_t)row * 256 + tid];
    float ss = v * v;
    #pragma unroll
    for (int s = 1; s < 64; s <<= 1) ss += __shfl_xor(ss, s);
    if ((tid & 63) == 0) p1[tid >> 6] = ss;
    __syncthreads();
    float tot = p1[0] + p1[1] + p1[2] + p1[3];
    float inv = 1.0f / sqrtf(tot);
    float val = v * inv - center[tid];
    unsigned short hb = bf16_rn(val);
    float hf = __uint_as_float((unsigned int)hb << 16);
    float al = val - hf;
    Ah[(size_t)row * 256 + tid] = hb;
    xqf[(size_t)row * 256 + tid] = val;
    float ss2 = val * val, sal = al * al;
    #pragma unroll
    for (int s = 1; s < 64; s <<= 1) {
        ss2 += __shfl_xor(ss2, s);
        sal += __shfl_xor(sal, s);
    }
    if ((tid & 63) == 0) { p2[tid >> 6] = ss2; p3[tid >> 6] = sal; }
    __syncthreads();
    if (tid == 0) {
        q2a[row]  = p2[0] + p2[1] + p2[2] + p2[3];
        al2q[row] = p3[0] + p3[1] + p3[2] + p3[3];
    }
}

// ---------------------------------------------------------------------------
// Fused conversion + GEMM. Block = (n-tile of 128 train rows) x (m-half of
// 512 queries). LDS: Bsf 64 KB (4 K-subtiles, layout [row][chunk^(row&7)] in
// 16B chunks, identical to the verified reader), As 2x16 KB, xnl 512 B.
// ---------------------------------------------------------------------------
__global__ __launch_bounds__(256, 1) void fused_tile(
    const float* __restrict__ X, const unsigned short* __restrict__ Ah,
    float* __restrict__ xn2, float* __restrict__ gmin,
    unsigned int* __restrict__ scal,
    int Mp, int Np, int nb_train, int B, int ntiles)
{
    __shared__ unsigned short Bsf[4 * 128 * 64];   // 64 KB, [ks][row][slot]
    __shared__ unsigned short As[2][128 * 64];     // 32 KB
    __shared__ float xnl[128];
    __shared__ float mx4[4];

    // bijective chunked XCD swizzle: pair (nt, mh 0/1) adjacent, same XCD.
    const int nwg  = ntiles * 2;
    const int orig = blockIdx.x;
    const int xcd  = orig & 7;
    const int pos  = orig >> 3;
    const int q8   = nwg >> 3, r8 = nwg & 7;
    const int wg   = (xcd < r8 ? xcd * (q8 + 1) : r8 * (q8 + 1) + (xcd - r8) * q8) + pos;
    if (wg >= nwg) return;
    const int nt = wg >> 1, mh = wg & 1;
    const int ntile = nt * 128;

    const int tid  = threadIdx.x;
    const int wave = tid >> 6;
    const int lane = tid & 63;

    // ================= Phase 1: convert X n-tile into LDS ==================
    {
        const int r = tid >> 1, h = tid & 1;       // row, dim-half (128 floats)
        const int grow = ntile + r;
        const bool pad = (grow >= nb_train);
        float ss = 0.f;
        if (!pad) {
            const float4* src = (const float4*)(X + (size_t)grow * 256 + h * 128);
            #pragma unroll
            for (int g2 = 0; g2 < 8; ++g2) {       // 2 chunks (4 float4) per iter
                float4 f0 = src[g2 * 4 + 0], f1 = src[g2 * 4 + 1];
                float4 f2 = src[g2 * 4 + 2], f3 = src[g2 * 4 + 3];
                short8 c0, c1;
                c0[0] = bf16_rn(f0.x); c0[1] = bf16_rn(f0.y);
                c0[2] = bf16_rn(f0.z); c0[3] = bf16_rn(f0.w);
                c0[4] = bf16_rn(f1.x); c0[5] = bf16_rn(f1.y);
                c0[6] = bf16_rn(f1.z); c0[7] = bf16_rn(f1.w);
                c1[0] = bf16_rn(f2.x); c1[1] = bf16_rn(f2.y);
                c1[2] = bf16_rn(f2.z); c1[3] = bf16_rn(f2.w);
                c1[4] = bf16_rn(f3.x); c1[5] = bf16_rn(f3.y);
                c1[6] = bf16_rn(f3.z); c1[7] = bf16_rn(f3.w);
                const int C0 = h * 16 + g2 * 2, C1 = C0 + 1;
                *(short8*)&Bsf[(C0 >> 3) * 8192 + r * 64 + ((C0 & 7) ^ (r & 7)) * 8] = c0;
                *(short8*)&Bsf[(C1 >> 3) * 8192 + r * 64 + ((C1 & 7) ^ (r & 7)) * 8] = c1;
                ss += f0.x * f0.x + f0.y * f0.y + f0.z * f0.z + f0.w * f0.w
                    + f1.x * f1.x + f1.y * f1.y + f1.z * f1.z + f1.w * f1.w
                    + f2.x * f2.x + f2.y * f2.y + f2.z * f2.z + f2.w * f2.w
                    + f3.x * f3.x + f3.y * f3.y + f3.z * f3.z + f3.w * f3.w;
            }
        } else {
            short8 z = {0, 0, 0, 0, 0, 0, 0, 0};
            #pragma unroll
            for (int g2 = 0; g2 < 8; ++g2) {
                const int C0 = h * 16 + g2 * 2, C1 = C0 + 1;
                *(short8*)&Bsf[(C0 >> 3) * 8192 + r * 64 + ((C0 & 7) ^ (r & 7)) * 8] = z;
                *(short8*)&Bsf[(C1 >> 3) * 8192 + r * 64 + ((C1 & 7) ^ (r & 7)) * 8] = z;
            }
        }
        float tot = ss + __shfl_xor(ss, 1);        // combine the two halves
        float xv  = pad ? 3.0e38f : tot;
        if (h == 0) {
            xnl[r] = xv;
            if (mh == 0) xn2[grow] = xv;
        }
        // block max of real norms (pads excluded) for the error bound
        float c = (h == 0 && !pad) ? tot : 0.f;
        #pragma unroll
        for (int s = 1; s < 64; s <<= 1) c = fmaxf(c, __shfl_xor(c, s));
        if (lane == 0) mx4[wave] = c;
    }

    // ================= Phase 2: m-loop GEMM, A-only staging =================
    const int mq = (wave >> 1) * 64;
    const int nq = (wave & 1) * 64;
    const int lrow = lane & 15;
    const int kseg = lane >> 4;
    const int sw = lrow & 7;
    const int srow = lane >> 3;                    // staging row-in-segment
    const int schk = ((lane & 7) ^ (lane >> 3)) * 8;
    const int ng64 = Np >> 6;
    const int gb   = (ntile + nq) >> 6;

    auto stageA = [&](int s) {                     // 16 KB: 128 rows x 64 dims
        const int mt2 = s >> 2, ks2 = s & 3;
        const int mbase = (mh * 4 + mt2) * 128;
        unsigned short* dbuf = As[s & 1];
        #pragma unroll
        for (int q = 0; q < 4; ++q) {
            const int s8 = wave * 4 + q;
            const unsigned short* src =
                Ah + (size_t)(mbase + s8 * 8 + srow) * 256 + ks2 * 64 + schk;
            gload_lds16(src, dbuf + s8 * 512);
        }
    };

    float4v acc[4][4];
    #pragma unroll
    for (int i = 0; i < 4; ++i)
        #pragma unroll
        for (int j = 0; j < 4; ++j)
            acc[i][j] = (float4v){0.f, 0.f, 0.f, 0.f};

    stageA(0);
    __syncthreads();                               // conversion + stage(0) done
    if (tid == 0 && mh == 0) {
        float m = fmaxf(fmaxf(mx4[0], mx4[1]), fmaxf(mx4[2], mx4[3]));
        if (m > 0.f) atomicMax(scal, __float_as_uint(m));
    }

    for (int s = 0; s < 16; ++s) {
        if (s + 1 < 16) stageA(s + 1);             // flies under compute(s)
        const unsigned short* Ab = As[s & 1];
        const unsigned short* Bb = &Bsf[(s & 3) * 8192];
        #pragma unroll
        for (int t = 0; t < 2; ++t) {
            const int wch = ((t * 4 + kseg) ^ sw) * 8;
            short8 a[4], b[4];
            #pragma unroll
            for (int i = 0; i < 4; ++i)
                a[i] = *(const short8*)&Ab[(mq + i * 16 + lrow) * 64 + wch];
            #pragma unroll
            for (int j = 0; j < 4; ++j)
                b[j] = *(const short8*)&Bb[(nq + j * 16 + lrow) * 64 + wch];
            #pragma unroll
            for (int i = 0; i < 4; ++i)
                #pragma unroll
                for (int j = 0; j < 4; ++j)
                    acc[i][j] = __builtin_amdgcn_mfma_f32_16x16x32_bf16(
                        a[i], b[j], acc[i][j], 0, 0, 0);
        }
        __syncthreads();                           // drains stage(s+1) too

        if ((s & 3) == 3) {                        // epilogue for m-tile s>>2
            const int mtile = (mh * 4 + (s >> 2)) * 128;
            float xnv[4];
            #pragma unroll
            for (int j = 0; j < 4; ++j)
                xnv[j] = xnl[nq + j * 16 + lrow];
            #pragma unroll
            for (int i = 0; i < 4; ++i) {
                #pragma unroll
                for (int r = 0; r < 4; ++r) {
                    const int lm = mq + i * 16 + kseg * 4 + r;
                    const int gq = mtile + lm;
                    float vm = fminf(
                        fminf(xnv[0] - 2.0f * acc[i][0][r], xnv[1] - 2.0f * acc[i][1][r]),
                        fminf(xnv[2] - 2.0f * acc[i][2][r], xnv[3] - 2.0f * acc[i][3][r]));
                    #pragma unroll
                    for (int sft = 1; sft < 16; sft <<= 1)
                        vm = fminf(vm, __shfl_xor(vm, sft));
                    if (lrow == 0 && gq < B)
                        gmin[(size_t)gq * ng64 + gb] = vm;
                }
            }
            #pragma unroll
            for (int i = 0; i < 4; ++i)
                #pragma unroll
                for (int j = 0; j < 4; ++j)
                    acc[i][j] = (float4v){0.f, 0.f, 0.f, 0.f};
        }
    }
}

// One block per query: approx minima -> window from rigorous bound -> exact
// fp32 rescore of candidate 64-row groups -> fused conformal classification.
__global__ __launch_bounds__(256) void select_classify(
    const float* __restrict__ gmin, const float* __restrict__ xqf,
    const float* __restrict__ X, const float* __restrict__ xn2,
    const float* __restrict__ q2a, const float* __restrict__ al2q,
    const unsigned int* __restrict__ scal,
    const int* __restrict__ labels, const int* __restrict__ nbr,
    const int* __restrict__ cali, float* __restrict__ out,
    int Np, int nb_train, int knm1, int nb_cali, int B)
{
    extern __shared__ float gbuf[];            // ng64 floats
    __shared__ float xq_s[256];
    __shared__ float wmin[4], fsc[4];
    __shared__ int   fid[4];
    __shared__ float s_thr;
    __shared__ int   cand[256];
    __shared__ int   s_ncand;
    __shared__ int   s_closest;

    const int q    = blockIdx.x;
    const int tid  = threadIdx.x;
    const int lane = tid & 63;
    const int wave = tid >> 6;
    const int ng64 = Np >> 6;

    if (tid == 0) s_ncand = 0;
    xq_s[tid] = xqf[(size_t)q * 256 + tid];
    float vmin = 3.4e38f;
    for (int i = tid; i < ng64; i += 256) {
        float v = gmin[(size_t)q * ng64 + i];
        gbuf[i] = v;
        vmin = fminf(vmin, v);
    }
    #pragma unroll
    for (int s = 1; s < 64; s <<= 1) vmin = fminf(vmin, __shfl_xor(vmin, s));
    if (lane == 0) wmin[wave] = vmin;
    __syncthreads();
    if (tid == 0) {
        float m = fminf(fminf(wmin[0], wmin[1]), fminf(wmin[2], wmin[3]));
        float maxb  = sqrtf(__uint_as_float(scal[0]));
        float maxbl = maxb * 0.00390625f;          // ||Bl|| <= 2^-8 ||B||, rigorous
        float an = sqrtf(q2a[q]), al = sqrtf(al2q[q]);
        float errdot = al * maxb * 1.00390625f + (an + al) * maxbl;
        s_thr = m + 4.0f * errdot + 1e-3f;
    }
    __syncthreads();
    const float thr = s_thr;
    for (int g = tid; g < ng64; g += 256) {
        if (gbuf[g] <= thr) {
            int p = atomicAdd(&s_ncand, 1);
            if (p < 256) cand[p] = g;
        }
    }
    __syncthreads();
    const int nc = s_ncand;

    // exact rescore: 4 lanes per row (dim quarters), 64 rows per group.
    const int rsub = tid & 3;
    const int rrow = tid >> 2;
    float bsc = 3.4e38f; int bidx = 0x7FFFFFFF;
    auto rescore = [&](int g) {
        int row = g * 64 + rrow;
        if (row < nb_train) {
            const float* xr = X + (size_t)row * 256 + rsub * 64;
            const float* xs = xq_s + rsub * 64;
            float dot = 0.f;
            #pragma unroll
            for (int k = 0; k < 16; ++k) {
                float4 a4 = *(const float4*)(xs + k * 4);
                float4 b4 = *(const float4*)(xr + k * 4);
                dot += a4.x * b4.x + a4.y * b4.y + a4.z * b4.z + a4.w * b4.w;
            }
            dot += __shfl_xor(dot, 1);
            dot += __shfl_xor(dot, 2);
            float sc = xn2[row] - 2.0f * dot;
            if (sc < bsc || (sc == bsc && row < bidx)) { bsc = sc; bidx = row; }
        }
    };
    if (nc <= 256) {
        for (int c = 0; c < nc; ++c) rescore(cand[c]);
    } else {
        for (int g = 0; g < ng64; ++g)
            if (gbuf[g] <= thr) rescore(g);      // correctness backstop
    }
    #pragma unroll
    for (int s = 1; s < 64; s <<= 1) {
        float osc = __shfl_xor(bsc, s);
        int   oid = __shfl_xor(bidx, s);
        if (osc < bsc || (osc == bsc && oid < bidx)) { bsc = osc; bidx = oid; }
    }
    if (lane == 0) { fsc[wave] = bsc; fid[wave] = bidx; }
    __syncthreads();
    if (tid == 0) {
        float bs = fsc[0]; int bi = fid[0];
        #pragma unroll
        for (int w = 1; w < 4; ++w)
            if (fsc[w] < bs || (fsc[w] == bs && fid[w] < bi)) { bs = fsc[w]; bi = fid[w]; }
        s_closest = bi;
    }
    __syncthreads();

    if (wave == 0) {
        const int closest = s_closest;
        const int K = knm1 + 1;   // 75
        int lbl0 = -1, lbl1 = -1;
        if (lane < K) {
            int idx = (lane == 0) ? closest : nbr[(size_t)closest * knm1 + (lane - 1)];
            lbl0 = labels[idx];
        }
        int j2 = lane + 64;
        if (j2 < K) {
            int idx = nbr[(size_t)closest * knm1 + (j2 - 1)];
            lbl1 = labels[idx];
        }
        int bestc = 0, bestp = -1;
        #pragma unroll
        for (int c = 0; c < 10; ++c) {
            int cnt = __popcll(__ballot(lbl0 == c)) + __popcll(__ballot(lbl1 == c));
            int v = K - cnt;
            int lo = 0, hi = nb_cali;
            while (lo < hi) {             // bisect_left
                int mid = (lo + hi) >> 1;
                if (cali[mid] < v) lo = mid + 1; else hi = mid;
            }
            int p = nb_cali - lo;
            if (p > bestp) { bestp = p; bestc = c; }
        }
        float pv = (float)bestp / (float)nb_cali;
        if (lane < 10)
            out[(size_t)q * 10 + lane] = (lane == bestc) ? pv : 0.0f;
    }
}

extern "C" void kernel_launch(void* const* d_in, const int* in_sizes, int n_in,
                              void* d_out, int out_size, void* d_ws, size_t ws_size,
                              hipStream_t stream) {
    const float* x      = (const float*)d_in[0];
    const float* X      = (const float*)d_in[1];
    const float* center = (const float*)d_in[2];
    const int* labels   = (const int*)d_in[3];
    const int* nbr      = (const int*)d_in[4];
    const int* cali     = (const int*)d_in[5];
    float* out = (float*)d_out;

    const int d        = in_sizes[2];              // 256
    const int B        = in_sizes[0] / d;          // 1024
    const int nb_train = in_sizes[3];              // 100000
    const int knm1     = in_sizes[4] / nb_train;   // 74
    const int nb_cali  = in_sizes[5];              // 1000

    const int Mp = (B + 127) & ~127;               // 1024
    const int Np = (nb_train + 127) & ~127;        // 100096
    const int ng64 = Np >> 6;                      // 1564

    char* ws = (char*)d_ws;
    size_t off = 0;
    float* gmin = (float*)(ws + off);          off += (size_t)Mp * ng64 * 4;
    unsigned short* Ah = (unsigned short*)(ws + off); off += (size_t)Mp * 256 * 2;
    float* xqf  = (float*)(ws + off);          off += (size_t)Mp * 256 * 4;
    float* q2a  = (float*)(ws + off);          off += (size_t)Mp * 4;
    float* al2q = (float*)(ws + off);          off += (size_t)Mp * 4;
    float* xn2  = (float*)(ws + off);          off += (size_t)Np * 4;
    unsigned int* scal = (unsigned int*)(ws + off); off += 8;

    hipMemsetAsync(scal, 0, 8, stream);

    prep_q<<<Mp, 256, 0, stream>>>(x, center, Ah, xqf, q2a, al2q, B, Mp);

    const int ntiles = Np / 128;                   // 782
    fused_tile<<<ntiles * 2, 256, 0, stream>>>(
        X, Ah, xn2, gmin, scal, Mp, Np, nb_train, B, ntiles);

    select_classify<<<B, 256, ng64 * 4, stream>>>(
        gmin, xqf, X, xn2, q2a, al2q, scal, labels, nbr, cali, out,
        Np, nb_train, knm1, nb_cali, B);
}

// Round 8
// 407.610 us; speedup vs baseline: 1.0280x; 1.0280x over previous
//
#include <hip/hip_runtime.h>
#include <stdint.h>

// ---------------------------------------------------------------------------
// DkNN round 12: revert to the verified round-9 split structure (mfma_tile and
// select_classify byte-identical); rewrite prep's train side into a pure
// streaming BW shape: 8 rows/block, 32 lanes/row, 8 contiguous floats/thread
// (2x float4 loads + 1x 16B short8 store, 5-level shfl row-reduce).
// prep was measured 83 us at 1.85 TB/s combined (3.4x off roofline).
// ---------------------------------------------------------------------------

typedef __attribute__((ext_vector_type(8))) short short8;   // 8 bf16 = 4 VGPR
typedef __attribute__((ext_vector_type(4))) float float4v;  // MFMA C/D

static __device__ __forceinline__ unsigned short bf16_rn(float f) {
    unsigned int u = __float_as_uint(f);
    unsigned int r = (u + 0x7FFFu + ((u >> 16) & 1u)) >> 16;
    return (unsigned short)r;
}

static __device__ __forceinline__ void gload_lds16(const void* g, void* l) {
    __builtin_amdgcn_global_load_lds(
        (const __attribute__((address_space(1))) unsigned int*)g,
        (__attribute__((address_space(3))) unsigned int*)l, 16, 0, 0);
}

// blocks [0, train_rb): 8 train rows each (32 lanes/row, 8 floats/lane);
// blocks [train_rb, train_rb+Mp): one query row each.
__global__ __launch_bounds__(256) void prep_all(
    const float* __restrict__ X, const float* __restrict__ x,
    const float* __restrict__ center,
    unsigned short* __restrict__ Bh, float* __restrict__ xn2,
    unsigned short* __restrict__ Ah, float* __restrict__ xqf,
    float* __restrict__ q2a, float* __restrict__ al2q,
    unsigned int* __restrict__ scal,
    int nb_train, int Np, int B, int Mp, int train_rb)
{
    const int tid = threadIdx.x;
    __shared__ float smax[8];
    __shared__ float p1[4], p2[4], p3[4];

    if ((int)blockIdx.x < train_rb) {
        // ---- train side: row r = blk*8 + tid/32, lane8 = tid&31 owns 8 floats
        const int r     = blockIdx.x * 8 + (tid >> 5);
        const int lane8 = tid & 31;
        if (r >= nb_train) {
            short8 z = {0, 0, 0, 0, 0, 0, 0, 0};
            *(short8*)(Bh + (size_t)r * 256 + lane8 * 8) = z;
            if (lane8 == 0) { xn2[r] = 3.0e38f; smax[tid >> 5] = 0.f; }
        } else {
            const float4* src = (const float4*)(X + (size_t)r * 256 + lane8 * 8);
            float4 v0 = src[0];
            float4 v1 = src[1];
            short8 h;
            h[0] = bf16_rn(v0.x); h[1] = bf16_rn(v0.y);
            h[2] = bf16_rn(v0.z); h[3] = bf16_rn(v0.w);
            h[4] = bf16_rn(v1.x); h[5] = bf16_rn(v1.y);
            h[6] = bf16_rn(v1.z); h[7] = bf16_rn(v1.w);
            *(short8*)(Bh + (size_t)r * 256 + lane8 * 8) = h;
            float ss = v0.x * v0.x + v0.y * v0.y + v0.z * v0.z + v0.w * v0.w
                     + v1.x * v1.x + v1.y * v1.y + v1.z * v1.z + v1.w * v1.w;
            ss += __shfl_xor(ss, 1);
            ss += __shfl_xor(ss, 2);
            ss += __shfl_xor(ss, 4);
            ss += __shfl_xor(ss, 8);
            ss += __shfl_xor(ss, 16);          // within aligned 32-lane group
            if (lane8 == 0) { xn2[r] = ss; smax[tid >> 5] = ss; }
        }
        __syncthreads();
        if (tid == 0) {
            float m = smax[0];
            #pragma unroll
            for (int i = 1; i < 8; ++i) m = fmaxf(m, smax[i]);
            if (m > 0.f) atomicMax(scal, __float_as_uint(m));
        }
        return;
    }
    // ---- query side: one row per block, 256 threads (d=256) ----
    int row = blockIdx.x - train_rb;
    if (row >= Mp) return;
    if (row >= B) {
        Ah[(size_t)row * 256 + tid] = 0;
        xqf[(size_t)row * 256 + tid] = 0.f;
        if (tid == 0) { q2a[row] = 0.f; al2q[row] = 0.f; }
        return;
    }
    float v = x[(size_t)row * 256 + tid];
    float ss = v * v;
    #pragma unroll
    for (int s = 1; s < 64; s <<= 1) ss += __shfl_xor(ss, s);
    if ((tid & 63) == 0) p1[tid >> 6] = ss;
    __syncthreads();
    float tot = p1[0] + p1[1] + p1[2] + p1[3];
    float inv = 1.0f / sqrtf(tot);
    float val = v * inv - center[tid];
    unsigned short hb = bf16_rn(val);
    float hf = __uint_as_float((unsigned int)hb << 16);
    float al = val - hf;
    Ah[(size_t)row * 256 + tid] = hb;
    xqf[(size_t)row * 256 + tid] = val;
    float ss2 = val * val, sal = al * al;
    #pragma unroll
    for (int s = 1; s < 64; s <<= 1) {
        ss2 += __shfl_xor(ss2, s);
        sal += __shfl_xor(sal, s);
    }
    if ((tid & 63) == 0) { p2[tid >> 6] = ss2; p3[tid >> 6] = sal; }
    __syncthreads();
    if (tid == 0) {
        q2a[row]  = p2[0] + p2[1] + p2[2] + p2[3];
        al2q[row] = p3[0] + p3[1] + p3[2] + p3[3];
    }
}

// 128x128 tile, 4 waves each computing a 64x64 quadrant (4x4 frags of 16x16x32).
// Single pass Ah*Bh, 4 K-steps of BK=64. Epilogue: per-(query, 64-col group)
// min of xn2 - 2*dot -> gmin (exclusive ownership, scalar stores).
__global__ __launch_bounds__(256, 4) void mfma_tile(
    const unsigned short* __restrict__ Adata,  // Ah, Mp*256
    const unsigned short* __restrict__ Bdata,  // Bh, Np*256
    const float* __restrict__ xn2,
    float* __restrict__ gmin,
    int Mp, int Np, int nb_train, int B,
    int ntiles, int nper, int mtiles)
{
    __shared__ unsigned short As[128 * 64];   // [row][chunk ^ (row&7)] 16B chunks
    __shared__ unsigned short Bs[128 * 64];

    const int bid = blockIdx.x;
    const int xcd = bid & 7;
    const int s_  = bid >> 3;
    const int n_t = xcd * nper + (s_ / mtiles);
    const int m_t = s_ - (s_ / mtiles) * mtiles;
    if (n_t >= ntiles) return;
    const int mtile = m_t * 128;
    const int ntile = n_t * 128;

    const int tid  = threadIdx.x;
    const int wave = tid >> 6;
    const int lane = tid & 63;

    // ---- staging role: waves 0,1 stage A rows [0:64),[64:128); waves 2,3 for B
    const int isB   = wave >> 1;
    const int Rwave = (wave & 1) * 64;
    const int lrow8  = lane >> 3;
    const int lchunk = lane & 7;
    const unsigned short* sbase = isB
        ? (Bdata + (size_t)(ntile + Rwave + lrow8) * 256 + (size_t)((lchunk ^ lrow8) * 8))
        : (Adata + (size_t)(mtile + Rwave + lrow8) * 256 + (size_t)((lchunk ^ lrow8) * 8));
    unsigned short* lwave = (isB ? Bs : As) + Rwave * 64;

    // ---- compute role: quadrant
    const int mq = (wave >> 1) * 64;
    const int nq = (wave & 1) * 64;
    const int lrow = lane & 15;
    const int kseg = lane >> 4;
    const int sw = lrow & 7;

    float4v acc[4][4];
    #pragma unroll
    for (int i = 0; i < 4; ++i)
        #pragma unroll
        for (int j = 0; j < 4; ++j)
            acc[i][j] = (float4v){0.f, 0.f, 0.f, 0.f};

    for (int s = 0; s < 4; ++s) {
        const unsigned short* g = sbase + (size_t)(s * 64);
        __syncthreads();
        #pragma unroll
        for (int q = 0; q < 8; ++q)
            gload_lds16(g + q * 2048, lwave + q * 512);
        __syncthreads();
        #pragma unroll
        for (int t = 0; t < 2; ++t) {
            const int wch = ((t * 4 + kseg) ^ sw) * 8;
            short8 a[4], b[4];
            #pragma unroll
            for (int i = 0; i < 4; ++i)
                a[i] = *(const short8*)&As[(mq + i * 16 + lrow) * 64 + wch];
            #pragma unroll
            for (int j = 0; j < 4; ++j)
                b[j] = *(const short8*)&Bs[(nq + j * 16 + lrow) * 64 + wch];
            #pragma unroll
            for (int i = 0; i < 4; ++i)
                #pragma unroll
                for (int j = 0; j < 4; ++j)
                    acc[i][j] = __builtin_amdgcn_mfma_f32_16x16x32_bf16(
                        a[i], b[j], acc[i][j], 0, 0, 0);
        }
    }

    // ---- epilogue: per-(q, 64-col group) min of xn2 - 2*dot ----
    const int ng64 = Np >> 6;
    const int gb = (ntile + nq) >> 6;       // this wave's group index
    float xnv[4];
    #pragma unroll
    for (int j = 0; j < 4; ++j)
        xnv[j] = xn2[ntile + nq + j * 16 + lrow];   // pads hold 3e38

    #pragma unroll
    for (int i = 0; i < 4; ++i) {
        #pragma unroll
        for (int r = 0; r < 4; ++r) {
            const int lm = mq + i * 16 + kseg * 4 + r;   // block-local query
            const int gq = mtile + lm;
            float vm = fminf(
                fminf(xnv[0] - 2.0f * acc[i][0][r], xnv[1] - 2.0f * acc[i][1][r]),
                fminf(xnv[2] - 2.0f * acc[i][2][r], xnv[3] - 2.0f * acc[i][3][r]));
            #pragma unroll
            for (int sft = 1; sft < 16; sft <<= 1)
                vm = fminf(vm, __shfl_xor(vm, sft));
            if (lrow == 0 && gq < B)
                gmin[(size_t)gq * ng64 + gb] = vm;
        }
    }
}

// One block per query: approx minima -> window from rigorous bound -> exact
// fp32 rescore of candidate 64-row groups -> fused conformal classification.
__global__ __launch_bounds__(256) void select_classify(
    const float* __restrict__ gmin, const float* __restrict__ xqf,
    const float* __restrict__ X, const float* __restrict__ xn2,
    const float* __restrict__ q2a, const float* __restrict__ al2q,
    const unsigned int* __restrict__ scal,
    const int* __restrict__ labels, const int* __restrict__ nbr,
    const int* __restrict__ cali, float* __restrict__ out,
    int Np, int nb_train, int knm1, int nb_cali, int B)
{
    extern __shared__ float gbuf[];            // ng64 floats
    __shared__ float xq_s[256];
    __shared__ float wmin[4], fsc[4];
    __shared__ int   fid[4];
    __shared__ float s_thr;
    __shared__ int   cand[256];
    __shared__ int   s_ncand;
    __shared__ int   s_closest;

    const int q    = blockIdx.x;
    const int tid  = threadIdx.x;
    const int lane = tid & 63;
    const int wave = tid >> 6;
    const int ng64 = Np >> 6;

    if (tid == 0) s_ncand = 0;
    xq_s[tid] = xqf[(size_t)q * 256 + tid];
    float vmin = 3.4e38f;
    for (int i = tid; i < ng64; i += 256) {
        float v = gmin[(size_t)q * ng64 + i];
        gbuf[i] = v;
        vmin = fminf(vmin, v);
    }
    #pragma unroll
    for (int s = 1; s < 64; s <<= 1) vmin = fminf(vmin, __shfl_xor(vmin, s));
    if (lane == 0) wmin[wave] = vmin;
    __syncthreads();
    if (tid == 0) {
        float m = fminf(fminf(wmin[0], wmin[1]), fminf(wmin[2], wmin[3]));
        float maxb  = sqrtf(__uint_as_float(scal[0]));
        float maxbl = maxb * 0.00390625f;          // ||Bl|| <= 2^-8 ||B||, rigorous
        float an = sqrtf(q2a[q]), al = sqrtf(al2q[q]);
        float errdot = al * maxb * 1.00390625f + (an + al) * maxbl;
        s_thr = m + 4.0f * errdot + 1e-3f;
    }
    __syncthreads();
    const float thr = s_thr;
    for (int g = tid; g < ng64; g += 256) {
        if (gbuf[g] <= thr) {
            int p = atomicAdd(&s_ncand, 1);
            if (p < 256) cand[p] = g;
        }
    }
    __syncthreads();
    const int nc = s_ncand;

    // exact rescore: 4 lanes per row (dim quarters), 64 rows per group.
    const int rsub = tid & 3;
    const int rrow = tid >> 2;
    float bsc = 3.4e38f; int bidx = 0x7FFFFFFF;
    auto rescore = [&](int g) {
        int row = g * 64 + rrow;
        if (row < nb_train) {
            const float* xr = X + (size_t)row * 256 + rsub * 64;
            const float* xs = xq_s + rsub * 64;
            float dot = 0.f;
            #pragma unroll
            for (int k = 0; k < 16; ++k) {
                float4 a4 = *(const float4*)(xs + k * 4);
                float4 b4 = *(const float4*)(xr + k * 4);
                dot += a4.x * b4.x + a4.y * b4.y + a4.z * b4.z + a4.w * b4.w;
            }
            dot += __shfl_xor(dot, 1);
            dot += __shfl_xor(dot, 2);
            float sc = xn2[row] - 2.0f * dot;
            if (sc < bsc || (sc == bsc && row < bidx)) { bsc = sc; bidx = row; }
        }
    };
    if (nc <= 256) {
        for (int c = 0; c < nc; ++c) rescore(cand[c]);
    } else {
        for (int g = 0; g < ng64; ++g)
            if (gbuf[g] <= thr) rescore(g);      // correctness backstop
    }
    #pragma unroll
    for (int s = 1; s < 64; s <<= 1) {
        float osc = __shfl_xor(bsc, s);
        int   oid = __shfl_xor(bidx, s);
        if (osc < bsc || (osc == bsc && oid < bidx)) { bsc = osc; bidx = oid; }
    }
    if (lane == 0) { fsc[wave] = bsc; fid[wave] = bidx; }
    __syncthreads();
    if (tid == 0) {
        float bs = fsc[0]; int bi = fid[0];
        #pragma unroll
        for (int w = 1; w < 4; ++w)
            if (fsc[w] < bs || (fsc[w] == bs && fid[w] < bi)) { bs = fsc[w]; bi = fid[w]; }
        s_closest = bi;
    }
    __syncthreads();

    if (wave == 0) {
        const int closest = s_closest;
        const int K = knm1 + 1;   // 75
        int lbl0 = -1, lbl1 = -1;
        if (lane < K) {
            int idx = (lane == 0) ? closest : nbr[(size_t)closest * knm1 + (lane - 1)];
            lbl0 = labels[idx];
        }
        int j2 = lane + 64;
        if (j2 < K) {
            int idx = nbr[(size_t)closest * knm1 + (j2 - 1)];
            lbl1 = labels[idx];
        }
        int bestc = 0, bestp = -1;
        #pragma unroll
        for (int c = 0; c < 10; ++c) {
            int cnt = __popcll(__ballot(lbl0 == c)) + __popcll(__ballot(lbl1 == c));
            int v = K - cnt;
            int lo = 0, hi = nb_cali;
            while (lo < hi) {             // bisect_left
                int mid = (lo + hi) >> 1;
                if (cali[mid] < v) lo = mid + 1; else hi = mid;
            }
            int p = nb_cali - lo;
            if (p > bestp) { bestp = p; bestc = c; }
        }
        float pv = (float)bestp / (float)nb_cali;
        if (lane < 10)
            out[(size_t)q * 10 + lane] = (lane == bestc) ? pv : 0.0f;
    }
}

extern "C" void kernel_launch(void* const* d_in, const int* in_sizes, int n_in,
                              void* d_out, int out_size, void* d_ws, size_t ws_size,
                              hipStream_t stream) {
    const float* x      = (const float*)d_in[0];
    const float* X      = (const float*)d_in[1];
    const float* center = (const float*)d_in[2];
    const int* labels   = (const int*)d_in[3];
    const int* nbr      = (const int*)d_in[4];
    const int* cali     = (const int*)d_in[5];
    float* out = (float*)d_out;

    const int d        = in_sizes[2];              // 256
    const int B        = in_sizes[0] / d;          // 1024
    const int nb_train = in_sizes[3];              // 100000
    const int knm1     = in_sizes[4] / nb_train;   // 74
    const int nb_cali  = in_sizes[5];              // 1000

    const int Mp = (B + 127) & ~127;               // 1024
    const int Np = (nb_train + 127) & ~127;        // 100096
    const int ng64 = Np >> 6;                      // 1564

    char* ws = (char*)d_ws;
    size_t off = 0;
    float* gmin = (float*)(ws + off);          off += (size_t)Mp * ng64 * 4;
    unsigned short* Ah = (unsigned short*)(ws + off); off += (size_t)Mp * 256 * 2;
    float* xqf  = (float*)(ws + off);          off += (size_t)Mp * 256 * 4;
    float* q2a  = (float*)(ws + off);          off += (size_t)Mp * 4;
    float* al2q = (float*)(ws + off);          off += (size_t)Mp * 4;
    unsigned short* Bh = (unsigned short*)(ws + off); off += (size_t)Np * 256 * 2;
    float* xn2  = (float*)(ws + off);          off += (size_t)Np * 4;
    unsigned int* scal = (unsigned int*)(ws + off); off += 8;

    hipMemsetAsync(scal, 0, 8, stream);

    const int train_rb = Np / 8;                   // 12512
    prep_all<<<train_rb + Mp, 256, 0, stream>>>(
        X, x, center, Bh, xn2, Ah, xqf, q2a, al2q, scal,
        nb_train, Np, B, Mp, train_rb);

    const int ntiles = Np / 128;                   // 782
    const int mtiles = Mp / 128;                   // 8
    const int nper   = (ntiles + 7) / 8;           // 98
    mfma_tile<<<8 * nper * mtiles, 256, 0, stream>>>(
        Ah, Bh, xn2, gmin, Mp, Np, nb_train, B, ntiles, nper, mtiles);

    select_classify<<<B, 256, ng64 * 4, stream>>>(
        gmin, xqf, X, xn2, q2a, al2q, scal, labels, nbr, cali, out,
        Np, nb_train, knm1, nb_cali, B);
}

// Round 9
// 304.782 us; speedup vs baseline: 1.3748x; 1.3374x over previous
//
#include <hip/hip_runtime.h>
#include <stdint.h>

// ---------------------------------------------------------------------------
// DkNN round 13: ILP-maximized prep, no atomics, no memset dispatch.
//  - prep_all train side: 64 rows/block; each thread owns 4 rows x 16 floats
//    -> 16 independent float4 loads in flight (Little's-law fix: R5 had 4,
//    R8's regression to 2 proved in-flight bytes is the lever). 2x short8
//    stores/row, 4-wide 16-lane shfl reduce, float4 xn2 store. Block max ->
//    pmax[bid] via PLAIN store (was: 6256-way same-address atomicMax).
//  - select_classify: reduces pmax[0..train_rb) for maxb (6KB, L3); thr
//    logic otherwise identical. scal + hipMemsetAsync eliminated (one fewer
//    dispatch gap).
//  - mfma_tile: byte-identical to verified round-9/12 kernel.
// ---------------------------------------------------------------------------

typedef __attribute__((ext_vector_type(8))) short short8;   // 8 bf16 = 4 VGPR
typedef __attribute__((ext_vector_type(4))) float float4v;  // MFMA C/D

static __device__ __forceinline__ unsigned short bf16_rn(float f) {
    unsigned int u = __float_as_uint(f);
    unsigned int r = (u + 0x7FFFu + ((u >> 16) & 1u)) >> 16;
    return (unsigned short)r;
}

static __device__ __forceinline__ void gload_lds16(const void* g, void* l) {
    __builtin_amdgcn_global_load_lds(
        (const __attribute__((address_space(1))) unsigned int*)g,
        (__attribute__((address_space(3))) unsigned int*)l, 16, 0, 0);
}

// blocks [0, train_rb): 64 train rows each (thread = 4 rows x 16 floats);
// blocks [train_rb, train_rb+Mp): one query row each.
__global__ __launch_bounds__(256) void prep_all(
    const float* __restrict__ X, const float* __restrict__ x,
    const float* __restrict__ center,
    unsigned short* __restrict__ Bh, float* __restrict__ xn2,
    unsigned short* __restrict__ Ah, float* __restrict__ xqf,
    float* __restrict__ q2a, float* __restrict__ al2q,
    float* __restrict__ pmax,
    int nb_train, int Np, int B, int Mp, int train_rb)
{
    const int tid = threadIdx.x;
    __shared__ float sm[4];
    __shared__ float p1[4], p2[4], p3[4];

    if ((int)blockIdx.x < train_rb) {
        const int seg = tid & 15;              // 16-float segment of the row
        const int rq  = tid >> 4;              // row-quad 0..15
        const int r0  = blockIdx.x * 64 + rq * 4;

        // ---- 16 independent float4 loads (4 rows x 4) ----
        float4 v[4][4];
        bool ok[4];
        #pragma unroll
        for (int rr = 0; rr < 4; ++rr) {
            ok[rr] = (r0 + rr < nb_train);
            if (ok[rr]) {
                const float4* s = (const float4*)(X + (size_t)(r0 + rr) * 256 + seg * 16);
                v[rr][0] = s[0]; v[rr][1] = s[1]; v[rr][2] = s[2]; v[rr][3] = s[3];
            }
        }
        // ---- convert + store + per-row partial sumsq ----
        float ss[4];
        #pragma unroll
        for (int rr = 0; rr < 4; ++rr) {
            if (ok[rr]) {
                short8 h0, h1;
                h0[0] = bf16_rn(v[rr][0].x); h0[1] = bf16_rn(v[rr][0].y);
                h0[2] = bf16_rn(v[rr][0].z); h0[3] = bf16_rn(v[rr][0].w);
                h0[4] = bf16_rn(v[rr][1].x); h0[5] = bf16_rn(v[rr][1].y);
                h0[6] = bf16_rn(v[rr][1].z); h0[7] = bf16_rn(v[rr][1].w);
                h1[0] = bf16_rn(v[rr][2].x); h1[1] = bf16_rn(v[rr][2].y);
                h1[2] = bf16_rn(v[rr][2].z); h1[3] = bf16_rn(v[rr][2].w);
                h1[4] = bf16_rn(v[rr][3].x); h1[5] = bf16_rn(v[rr][3].y);
                h1[6] = bf16_rn(v[rr][3].z); h1[7] = bf16_rn(v[rr][3].w);
                unsigned short* bp = Bh + (size_t)(r0 + rr) * 256 + seg * 16;
                *(short8*)bp = h0;
                *(short8*)(bp + 8) = h1;
                ss[rr] = v[rr][0].x * v[rr][0].x + v[rr][0].y * v[rr][0].y
                       + v[rr][0].z * v[rr][0].z + v[rr][0].w * v[rr][0].w
                       + v[rr][1].x * v[rr][1].x + v[rr][1].y * v[rr][1].y
                       + v[rr][1].z * v[rr][1].z + v[rr][1].w * v[rr][1].w
                       + v[rr][2].x * v[rr][2].x + v[rr][2].y * v[rr][2].y
                       + v[rr][2].z * v[rr][2].z + v[rr][2].w * v[rr][2].w
                       + v[rr][3].x * v[rr][3].x + v[rr][3].y * v[rr][3].y
                       + v[rr][3].z * v[rr][3].z + v[rr][3].w * v[rr][3].w;
            } else {
                short8 z = {0, 0, 0, 0, 0, 0, 0, 0};
                unsigned short* bp = Bh + (size_t)(r0 + rr) * 256 + seg * 16;
                *(short8*)bp = z;
                *(short8*)(bp + 8) = z;
                ss[rr] = 0.f;
            }
        }
        // ---- 16-lane row reduces (4 at once; groups are aligned in-wave) ----
        #pragma unroll
        for (int s = 1; s < 16; s <<= 1) {
            ss[0] += __shfl_xor(ss[0], s);
            ss[1] += __shfl_xor(ss[1], s);
            ss[2] += __shfl_xor(ss[2], s);
            ss[3] += __shfl_xor(ss[3], s);
        }
        float mx = 0.f;
        if (seg == 0) {
            #pragma unroll
            for (int rr = 0; rr < 4; ++rr) mx = fmaxf(mx, ok[rr] ? ss[rr] : 0.f);
            if (ok[3]) {
                *(float4*)(xn2 + r0) = make_float4(ss[0], ss[1], ss[2], ss[3]);
            } else {
                #pragma unroll
                for (int rr = 0; rr < 4; ++rr)
                    xn2[r0 + rr] = ok[rr] ? ss[rr] : 3.0e38f;
            }
        }
        // ---- block max -> pmax[bid] (plain store, reduced in select) ----
        #pragma unroll
        for (int s = 1; s < 64; s <<= 1) mx = fmaxf(mx, __shfl_xor(mx, s));
        if ((tid & 63) == 0) sm[tid >> 6] = mx;
        __syncthreads();
        if (tid == 0)
            pmax[blockIdx.x] = fmaxf(fmaxf(sm[0], sm[1]), fmaxf(sm[2], sm[3]));
        return;
    }
    // ---- query side: one row per block, 256 threads (d=256) ----
    int row = blockIdx.x - train_rb;
    if (row >= Mp) return;
    if (row >= B) {
        Ah[(size_t)row * 256 + tid] = 0;
        xqf[(size_t)row * 256 + tid] = 0.f;
        if (tid == 0) { q2a[row] = 0.f; al2q[row] = 0.f; }
        return;
    }
    float v = x[(size_t)row * 256 + tid];
    float ss = v * v;
    #pragma unroll
    for (int s = 1; s < 64; s <<= 1) ss += __shfl_xor(ss, s);
    if ((tid & 63) == 0) p1[tid >> 6] = ss;
    __syncthreads();
    float tot = p1[0] + p1[1] + p1[2] + p1[3];
    float inv = 1.0f / sqrtf(tot);
    float val = v * inv - center[tid];
    unsigned short hb = bf16_rn(val);
    float hf = __uint_as_float((unsigned int)hb << 16);
    float al = val - hf;
    Ah[(size_t)row * 256 + tid] = hb;
    xqf[(size_t)row * 256 + tid] = val;
    float ss2 = val * val, sal = al * al;
    #pragma unroll
    for (int s = 1; s < 64; s <<= 1) {
        ss2 += __shfl_xor(ss2, s);
        sal += __shfl_xor(sal, s);
    }
    if ((tid & 63) == 0) { p2[tid >> 6] = ss2; p3[tid >> 6] = sal; }
    __syncthreads();
    if (tid == 0) {
        q2a[row]  = p2[0] + p2[1] + p2[2] + p2[3];
        al2q[row] = p3[0] + p3[1] + p3[2] + p3[3];
    }
}

// 128x128 tile, 4 waves each computing a 64x64 quadrant (4x4 frags of 16x16x32).
// Single pass Ah*Bh, 4 K-steps of BK=64. Epilogue: per-(query, 64-col group)
// min of xn2 - 2*dot -> gmin (exclusive ownership, scalar stores).
__global__ __launch_bounds__(256, 4) void mfma_tile(
    const unsigned short* __restrict__ Adata,  // Ah, Mp*256
    const unsigned short* __restrict__ Bdata,  // Bh, Np*256
    const float* __restrict__ xn2,
    float* __restrict__ gmin,
    int Mp, int Np, int nb_train, int B,
    int ntiles, int nper, int mtiles)
{
    __shared__ unsigned short As[128 * 64];   // [row][chunk ^ (row&7)] 16B chunks
    __shared__ unsigned short Bs[128 * 64];

    const int bid = blockIdx.x;
    const int xcd = bid & 7;
    const int s_  = bid >> 3;
    const int n_t = xcd * nper + (s_ / mtiles);
    const int m_t = s_ - (s_ / mtiles) * mtiles;
    if (n_t >= ntiles) return;
    const int mtile = m_t * 128;
    const int ntile = n_t * 128;

    const int tid  = threadIdx.x;
    const int wave = tid >> 6;
    const int lane = tid & 63;

    // ---- staging role: waves 0,1 stage A rows [0:64),[64:128); waves 2,3 for B
    const int isB   = wave >> 1;
    const int Rwave = (wave & 1) * 64;
    const int lrow8  = lane >> 3;
    const int lchunk = lane & 7;
    const unsigned short* sbase = isB
        ? (Bdata + (size_t)(ntile + Rwave + lrow8) * 256 + (size_t)((lchunk ^ lrow8) * 8))
        : (Adata + (size_t)(mtile + Rwave + lrow8) * 256 + (size_t)((lchunk ^ lrow8) * 8));
    unsigned short* lwave = (isB ? Bs : As) + Rwave * 64;

    // ---- compute role: quadrant
    const int mq = (wave >> 1) * 64;
    const int nq = (wave & 1) * 64;
    const int lrow = lane & 15;
    const int kseg = lane >> 4;
    const int sw = lrow & 7;

    float4v acc[4][4];
    #pragma unroll
    for (int i = 0; i < 4; ++i)
        #pragma unroll
        for (int j = 0; j < 4; ++j)
            acc[i][j] = (float4v){0.f, 0.f, 0.f, 0.f};

    for (int s = 0; s < 4; ++s) {
        const unsigned short* g = sbase + (size_t)(s * 64);
        __syncthreads();
        #pragma unroll
        for (int q = 0; q < 8; ++q)
            gload_lds16(g + q * 2048, lwave + q * 512);
        __syncthreads();
        #pragma unroll
        for (int t = 0; t < 2; ++t) {
            const int wch = ((t * 4 + kseg) ^ sw) * 8;
            short8 a[4], b[4];
            #pragma unroll
            for (int i = 0; i < 4; ++i)
                a[i] = *(const short8*)&As[(mq + i * 16 + lrow) * 64 + wch];
            #pragma unroll
            for (int j = 0; j < 4; ++j)
                b[j] = *(const short8*)&Bs[(nq + j * 16 + lrow) * 64 + wch];
            #pragma unroll
            for (int i = 0; i < 4; ++i)
                #pragma unroll
                for (int j = 0; j < 4; ++j)
                    acc[i][j] = __builtin_amdgcn_mfma_f32_16x16x32_bf16(
                        a[i], b[j], acc[i][j], 0, 0, 0);
        }
    }

    // ---- epilogue: per-(q, 64-col group) min of xn2 - 2*dot ----
    const int ng64 = Np >> 6;
    const int gb = (ntile + nq) >> 6;       // this wave's group index
    float xnv[4];
    #pragma unroll
    for (int j = 0; j < 4; ++j)
        xnv[j] = xn2[ntile + nq + j * 16 + lrow];   // pads hold 3e38

    #pragma unroll
    for (int i = 0; i < 4; ++i) {
        #pragma unroll
        for (int r = 0; r < 4; ++r) {
            const int lm = mq + i * 16 + kseg * 4 + r;   // block-local query
            const int gq = mtile + lm;
            float vm = fminf(
                fminf(xnv[0] - 2.0f * acc[i][0][r], xnv[1] - 2.0f * acc[i][1][r]),
                fminf(xnv[2] - 2.0f * acc[i][2][r], xnv[3] - 2.0f * acc[i][3][r]));
            #pragma unroll
            for (int sft = 1; sft < 16; sft <<= 1)
                vm = fminf(vm, __shfl_xor(vm, sft));
            if (lrow == 0 && gq < B)
                gmin[(size_t)gq * ng64 + gb] = vm;
        }
    }
}

// One block per query: approx minima -> window from rigorous bound -> exact
// fp32 rescore of candidate 64-row groups -> fused conformal classification.
__global__ __launch_bounds__(256) void select_classify(
    const float* __restrict__ gmin, const float* __restrict__ xqf,
    const float* __restrict__ X, const float* __restrict__ xn2,
    const float* __restrict__ q2a, const float* __restrict__ al2q,
    const float* __restrict__ pmax,
    const int* __restrict__ labels, const int* __restrict__ nbr,
    const int* __restrict__ cali, float* __restrict__ out,
    int Np, int nb_train, int knm1, int nb_cali, int B, int train_rb)
{
    extern __shared__ float gbuf[];            // ng64 floats
    __shared__ float xq_s[256];
    __shared__ float wmin[4], wpm[4], fsc[4];
    __shared__ int   fid[4];
    __shared__ float s_thr;
    __shared__ int   cand[256];
    __shared__ int   s_ncand;
    __shared__ int   s_closest;

    const int q    = blockIdx.x;
    const int tid  = threadIdx.x;
    const int lane = tid & 63;
    const int wave = tid >> 6;
    const int ng64 = Np >> 6;

    if (tid == 0) s_ncand = 0;
    xq_s[tid] = xqf[(size_t)q * 256 + tid];
    float vmin = 3.4e38f;
    for (int i = tid; i < ng64; i += 256) {
        float v = gmin[(size_t)q * ng64 + i];
        gbuf[i] = v;
        vmin = fminf(vmin, v);
    }
    float pm = 0.f;
    for (int i = tid; i < train_rb; i += 256) pm = fmaxf(pm, pmax[i]);
    #pragma unroll
    for (int s = 1; s < 64; s <<= 1) {
        vmin = fminf(vmin, __shfl_xor(vmin, s));
        pm   = fmaxf(pm,   __shfl_xor(pm, s));
    }
    if (lane == 0) { wmin[wave] = vmin; wpm[wave] = pm; }
    __syncthreads();
    if (tid == 0) {
        float m = fminf(fminf(wmin[0], wmin[1]), fminf(wmin[2], wmin[3]));
        float mb2 = fmaxf(fmaxf(wpm[0], wpm[1]), fmaxf(wpm[2], wpm[3]));
        float maxb  = sqrtf(mb2);
        float maxbl = maxb * 0.00390625f;          // ||Bl|| <= 2^-8 ||B||, rigorous
        float an = sqrtf(q2a[q]), al = sqrtf(al2q[q]);
        float errdot = al * maxb * 1.00390625f + (an + al) * maxbl;
        s_thr = m + 4.0f * errdot + 1e-3f;
    }
    __syncthreads();
    const float thr = s_thr;
    for (int g = tid; g < ng64; g += 256) {
        if (gbuf[g] <= thr) {
            int p = atomicAdd(&s_ncand, 1);
            if (p < 256) cand[p] = g;
        }
    }
    __syncthreads();
    const int nc = s_ncand;

    // exact rescore: 4 lanes per row (dim quarters), 64 rows per group.
    const int rsub = tid & 3;
    const int rrow = tid >> 2;
    float bsc = 3.4e38f; int bidx = 0x7FFFFFFF;
    auto rescore = [&](int g) {
        int row = g * 64 + rrow;
        if (row < nb_train) {
            const float* xr = X + (size_t)row * 256 + rsub * 64;
            const float* xs = xq_s + rsub * 64;
            float dot = 0.f;
            #pragma unroll
            for (int k = 0; k < 16; ++k) {
                float4 a4 = *(const float4*)(xs + k * 4);
                float4 b4 = *(const float4*)(xr + k * 4);
                dot += a4.x * b4.x + a4.y * b4.y + a4.z * b4.z + a4.w * b4.w;
            }
            dot += __shfl_xor(dot, 1);
            dot += __shfl_xor(dot, 2);
            float sc = xn2[row] - 2.0f * dot;
            if (sc < bsc || (sc == bsc && row < bidx)) { bsc = sc; bidx = row; }
        }
    };
    if (nc <= 256) {
        for (int c = 0; c < nc; ++c) rescore(cand[c]);
    } else {
        for (int g = 0; g < ng64; ++g)
            if (gbuf[g] <= thr) rescore(g);      // correctness backstop
    }
    #pragma unroll
    for (int s = 1; s < 64; s <<= 1) {
        float osc = __shfl_xor(bsc, s);
        int   oid = __shfl_xor(bidx, s);
        if (osc < bsc || (osc == bsc && oid < bidx)) { bsc = osc; bidx = oid; }
    }
    if (lane == 0) { fsc[wave] = bsc; fid[wave] = bidx; }
    __syncthreads();
    if (tid == 0) {
        float bs = fsc[0]; int bi = fid[0];
        #pragma unroll
        for (int w = 1; w < 4; ++w)
            if (fsc[w] < bs || (fsc[w] == bs && fid[w] < bi)) { bs = fsc[w]; bi = fid[w]; }
        s_closest = bi;
    }
    __syncthreads();

    if (wave == 0) {
        const int closest = s_closest;
        const int K = knm1 + 1;   // 75
        int lbl0 = -1, lbl1 = -1;
        if (lane < K) {
            int idx = (lane == 0) ? closest : nbr[(size_t)closest * knm1 + (lane - 1)];
            lbl0 = labels[idx];
        }
        int j2 = lane + 64;
        if (j2 < K) {
            int idx = nbr[(size_t)closest * knm1 + (j2 - 1)];
            lbl1 = labels[idx];
        }
        int bestc = 0, bestp = -1;
        #pragma unroll
        for (int c = 0; c < 10; ++c) {
            int cnt = __popcll(__ballot(lbl0 == c)) + __popcll(__ballot(lbl1 == c));
            int v = K - cnt;
            int lo = 0, hi = nb_cali;
            while (lo < hi) {             // bisect_left
                int mid = (lo + hi) >> 1;
                if (cali[mid] < v) lo = mid + 1; else hi = mid;
            }
            int p = nb_cali - lo;
            if (p > bestp) { bestp = p; bestc = c; }
        }
        float pv = (float)bestp / (float)nb_cali;
        if (lane < 10)
            out[(size_t)q * 10 + lane] = (lane == bestc) ? pv : 0.0f;
    }
}

extern "C" void kernel_launch(void* const* d_in, const int* in_sizes, int n_in,
                              void* d_out, int out_size, void* d_ws, size_t ws_size,
                              hipStream_t stream) {
    const float* x      = (const float*)d_in[0];
    const float* X      = (const float*)d_in[1];
    const float* center = (const float*)d_in[2];
    const int* labels   = (const int*)d_in[3];
    const int* nbr      = (const int*)d_in[4];
    const int* cali     = (const int*)d_in[5];
    float* out = (float*)d_out;

    const int d        = in_sizes[2];              // 256
    const int B        = in_sizes[0] / d;          // 1024
    const int nb_train = in_sizes[3];              // 100000
    const int knm1     = in_sizes[4] / nb_train;   // 74
    const int nb_cali  = in_sizes[5];              // 1000

    const int Mp = (B + 127) & ~127;               // 1024
    const int Np = (nb_train + 127) & ~127;        // 100096
    const int ng64 = Np >> 6;                      // 1564

    char* ws = (char*)d_ws;
    size_t off = 0;
    float* gmin = (float*)(ws + off);          off += (size_t)Mp * ng64 * 4;
    unsigned short* Ah = (unsigned short*)(ws + off); off += (size_t)Mp * 256 * 2;
    float* xqf  = (float*)(ws + off);          off += (size_t)Mp * 256 * 4;
    float* q2a  = (float*)(ws + off);          off += (size_t)Mp * 4;
    float* al2q = (float*)(ws + off);          off += (size_t)Mp * 4;
    unsigned short* Bh = (unsigned short*)(ws + off); off += (size_t)Np * 256 * 2;
    float* xn2  = (float*)(ws + off);          off += (size_t)Np * 4;
    float* pmax = (float*)(ws + off);          off += (size_t)(Np / 64) * 4;

    const int train_rb = Np / 64;                  // 1564 blocks of 64 rows
    prep_all<<<train_rb + Mp, 256, 0, stream>>>(
        X, x, center, Bh, xn2, Ah, xqf, q2a, al2q, pmax,
        nb_train, Np, B, Mp, train_rb);

    const int ntiles = Np / 128;                   // 782
    const int mtiles = Mp / 128;                   // 8
    const int nper   = (ntiles + 7) / 8;           // 98
    mfma_tile<<<8 * nper * mtiles, 256, 0, stream>>>(
        Ah, Bh, xn2, gmin, Mp, Np, nb_train, B, ntiles, nper, mtiles);

    select_classify<<<B, 256, ng64 * 4, stream>>>(
        gmin, xqf, X, xn2, q2a, al2q, pmax, labels, nbr, cali, out,
        Np, nb_train, knm1, nb_cali, B, train_rb);
}